// Round 4
// baseline (2676.361 us; speedup 1.0000x reference)
//
#include <hip/hip_runtime.h>

#define NT 1024
#define TSEQ 512

__device__ __forceinline__ float sigmoid_(float x) { return 1.0f / (1.0f + __expf(-x)); }
__device__ __forceinline__ float tanh_(float x) { return 1.0f - 2.0f / (1.0f + __expf(2.0f * x)); }

// ---------------- prep kernel: pack weights into task-ordered image ----------------
// wbuf (float4): index (l*20 + j)*1024 + tid.
// Task map: f = tid/200 (k-chunk of 40), p = tid%200 (rows 2p, 2p+1). tid>=1000: zeros.
//   j in [0,10):  row 2p,   k-quad at 40f+4j
//   j in [10,20): row 2p+1, k-quad at 40f+4(j-10)
// Padded K=200 image: layer0 = [x(5); h(100); 0(95)], layers>=1 = [x(100); h(100)].
extern "C" __global__ void prep_weights(const float* __restrict__ Wih0,
                                        const float* __restrict__ Whh0,
                                        const float* __restrict__ WihL,
                                        const float* __restrict__ WhhL,
                                        float4* __restrict__ wbuf) {
    int gid = blockIdx.x * 256 + threadIdx.x;  // 5*20*1024 = 102400 total
    if (gid >= 102400) return;
    int tid = gid & 1023;
    int lj = gid >> 10;
    int j = lj % 20;
    int l = lj / 20;
    float tmp[4] = {0.f, 0.f, 0.f, 0.f};
    if (tid < 1000) {
        int f = tid / 200, p = tid % 200;
        int row = 2 * p + (j >= 10 ? 1 : 0);
        int q = (j >= 10) ? (j - 10) : j;
        int k0 = 40 * f + 4 * q;
        for (int c = 0; c < 4; ++c) {
            int k = k0 + c;
            float w = 0.f;
            if (l == 0) {
                if (k < 5) w = Wih0[row * 5 + k];
                else if (k < 105) w = Whh0[row * 100 + (k - 5)];
            } else {
                if (k < 100) w = WihL[(l - 1) * 40000 + row * 100 + k];
                else w = WhhL[(l - 1) * 40000 + row * 100 + (k - 100)];
            }
            tmp[c] = w;
        }
    }
    wbuf[gid] = make_float4(tmp[0], tmp[1], tmp[2], tmp[3]);
}

// ---------------- main kernel ----------------
// One block per batch element. Thread (f = tid/200, p = tid%200) owns rows 2p,2p+1
// over k in [40f, 40f+40) — 80 weights in registers via straight-line coalesced load.
// __launch_bounds__(1024,4): min 4 waves/EU -> RA budget 128 arch VGPRs (need ~107).
template <int IN, bool FIRST, bool STORE>
__device__ void run_layer(const float4* __restrict__ wl, const float* __restrict__ bL,
                          const float* __restrict__ xsrc, float* __restrict__ hdst,
                          int b, int tid, int f, int p,
                          float* xh, float* part) {
    // weights -> registers: branch-free, constant dest indices (SROA-guaranteed)
    float4 wA[10], wB[10];
#pragma unroll
    for (int q = 0; q < 10; ++q) wA[q] = wl[q * 1024 + tid];
#pragma unroll
    for (int q = 0; q < 10; ++q) wB[q] = wl[(10 + q) * 1024 + tid];

    // combine threads hold their unit's 4 biases in registers (no LDS round-trip)
    float bi = 0.f, bf = 0.f, bg = 0.f, bo = 0.f;
    if (tid < 100) {
        bi = bL[tid];
        bf = bL[100 + tid];
        bg = bL[200 + tid];
        bo = bL[300 + tid];
    }

    if (tid < 256) xh[tid] = 0.f;
    __syncthreads();
    if (FIRST) {
        if (tid < 5) xh[tid] = xsrc[b * TSEQ * 5 + tid];
    } else {
        if (tid < 25) ((float4*)xh)[tid] = ((const float4*)xsrc)[b * TSEQ * 25 + tid];
    }
    __syncthreads();

    const float4* xv4 = (const float4*)xh + f * 10;  // all-lane-same-address broadcast
    float c = 0.f, hprev = 0.f;

    for (int t = 0; t < TSEQ; ++t) {
        // delayed h-store: issued at phase top so barrier's vmcnt drain is cheap
        if (STORE) {
            if (tid < 100 && t > 0) hdst[(b * TSEQ + (t - 1)) * 100 + tid] = hprev;
        }
        // prefetch next-step input (landed after combine)
        int tn = (t + 1 < TSEQ) ? (t + 1) : (TSEQ - 1);
        float pfs = 0.f;
        float4 pf4 = {0.f, 0.f, 0.f, 0.f};
        if (FIRST) {
            if (tid >= 128 && tid < 133) pfs = xsrc[(b * TSEQ + tn) * 5 + (tid - 128)];
        } else {
            if (tid >= 128 && tid < 153) pf4 = ((const float4*)xsrc)[(b * TSEQ + tn) * 25 + (tid - 128)];
        }

        // 80 FMAs: 4 independent accumulation chains
        float aA0 = 0.f, aA1 = 0.f, aB0 = 0.f, aB1 = 0.f;
#pragma unroll
        for (int q = 0; q < 10; q += 2) {
            float4 x0 = xv4[q];
            float4 x1 = xv4[q + 1];
            aA0 = fmaf(wA[q].x, x0.x, aA0);
            aA0 = fmaf(wA[q].y, x0.y, aA0);
            aA0 = fmaf(wA[q].z, x0.z, aA0);
            aA0 = fmaf(wA[q].w, x0.w, aA0);
            aB0 = fmaf(wB[q].x, x0.x, aB0);
            aB0 = fmaf(wB[q].y, x0.y, aB0);
            aB0 = fmaf(wB[q].z, x0.z, aB0);
            aB0 = fmaf(wB[q].w, x0.w, aB0);
            aA1 = fmaf(wA[q + 1].x, x1.x, aA1);
            aA1 = fmaf(wA[q + 1].y, x1.y, aA1);
            aA1 = fmaf(wA[q + 1].z, x1.z, aA1);
            aA1 = fmaf(wA[q + 1].w, x1.w, aA1);
            aB1 = fmaf(wB[q + 1].x, x1.x, aB1);
            aB1 = fmaf(wB[q + 1].y, x1.y, aB1);
            aB1 = fmaf(wB[q + 1].z, x1.z, aB1);
            aB1 = fmaf(wB[q + 1].w, x1.w, aB1);
        }
        if (tid < 1000) {
            *(float2*)&part[f * 400 + 2 * p] = make_float2(aA0 + aA1, aB0 + aB1);
        }
        __syncthreads();

        // combine: gates + state update on threads 0..99
        if (tid < 100) {
            float s0 = bi, s1 = bf, s2 = bg, s3 = bo;
#pragma unroll
            for (int ff = 0; ff < 5; ++ff) {
                s0 += part[ff * 400 + tid];
                s1 += part[ff * 400 + 100 + tid];
                s2 += part[ff * 400 + 200 + tid];
                s3 += part[ff * 400 + 300 + tid];
            }
            float gi = sigmoid_(s0);
            float gf = sigmoid_(s1);
            float gg = tanh_(s2);
            float go = sigmoid_(s3);
            c = gf * c + gi * gg;
            float hv = go * tanh_(c);
            xh[IN + tid] = hv;
            hprev = hv;
        }
        // land prefetched x for t+1
        if (FIRST) {
            if (tid >= 128 && tid < 133) xh[tid - 128] = pfs;
        } else {
            if (tid >= 128 && tid < 153) ((float4*)xh)[tid - 128] = pf4;
        }
        __syncthreads();
    }
    if (STORE) {
        if (tid < 100) hdst[(b * TSEQ + TSEQ - 1) * 100 + tid] = hprev;
    }
}

extern "C" __global__ void __launch_bounds__(NT, 4)
gesture_lstm_kernel(const float* __restrict__ x,
                    const float4* __restrict__ wbuf,
                    const float* __restrict__ b0, const float* __restrict__ bLv,
                    const float* __restrict__ gamma, const float* __restrict__ beta,
                    const float* __restrict__ rmean, const float* __restrict__ rvar,
                    const float* __restrict__ W1, const float* __restrict__ b1,
                    const float* __restrict__ W2, const float* __restrict__ b2,
                    const float* __restrict__ W3, const float* __restrict__ b3,
                    float* __restrict__ out, float* __restrict__ hseq) {
    __shared__ __align__(16) float xh[256];
    __shared__ __align__(16) float part[5 * 400];
    __shared__ __align__(16) float hw[10000];

    int tid = threadIdx.x;
    int b = blockIdx.x;
    int f = tid / 200;  // 5 for dummies; their xv4 reads land in xh[200..240) (zeroed)
    int p = tid % 200;

    run_layer<5,   true,  true >(wbuf + 0 * 20480, b0,         x,    hseq, b, tid, f, p, xh, part);
    run_layer<100, false, true >(wbuf + 1 * 20480, bLv + 0,    hseq, hseq, b, tid, f, p, xh, part);
    run_layer<100, false, true >(wbuf + 2 * 20480, bLv + 400,  hseq, hseq, b, tid, f, p, xh, part);
    run_layer<100, false, true >(wbuf + 3 * 20480, bLv + 800,  hseq, hseq, b, tid, f, p, xh, part);
    run_layer<100, false, false>(wbuf + 4 * 20480, bLv + 1200, hseq, hseq, b, tid, f, p, xh, part);

    // ---- head: BN (inference) -> FC1+ReLU -> FC2+ReLU -> FC3 ----
    if (tid < 100) {
        float hv = xh[100 + tid];
        xh[tid] = (hv - rmean[tid]) * rsqrtf(rvar[tid] + 1e-5f) * gamma[tid] + beta[tid];
    }
    __syncthreads();

    for (int i = tid; i < 2500; i += NT) ((float4*)hw)[i] = ((const float4*)W1)[i];
    __syncthreads();
    if (tid < 100) {
        float acc = b1[tid];
#pragma unroll
        for (int k = 0; k < 100; ++k) acc = fmaf(hw[tid * 100 + k], xh[k], acc);
        part[tid] = fmaxf(acc, 0.0f);
    }
    __syncthreads();

    for (int i = tid; i < 2500; i += NT) ((float4*)hw)[i] = ((const float4*)W2)[i];
    __syncthreads();
    if (tid < 100) {
        float acc = b2[tid];
#pragma unroll
        for (int k = 0; k < 100; ++k) acc = fmaf(hw[tid * 100 + k], part[k], acc);
        part[400 + tid] = fmaxf(acc, 0.0f);
    }
    __syncthreads();

    if (tid < 3) {
        float acc = b3[tid];
#pragma unroll
        for (int k = 0; k < 100; ++k) acc = fmaf(W3[tid * 100 + k], part[400 + k], acc);
        out[b * 3 + tid] = acc;
    }
}

extern "C" void kernel_launch(void* const* d_in, const int* in_sizes, int n_in,
                              void* d_out, int out_size, void* d_ws, size_t ws_size,
                              hipStream_t stream) {
    const float* x     = (const float*)d_in[0];
    const float* Wih0  = (const float*)d_in[1];
    const float* Whh0  = (const float*)d_in[2];
    const float* b0    = (const float*)d_in[3];
    const float* WihL  = (const float*)d_in[4];
    const float* WhhL  = (const float*)d_in[5];
    const float* bLv   = (const float*)d_in[6];
    const float* gamma = (const float*)d_in[7];
    const float* beta  = (const float*)d_in[8];
    const float* rmean = (const float*)d_in[9];
    const float* rvar  = (const float*)d_in[10];
    const float* W1    = (const float*)d_in[11];
    const float* b1    = (const float*)d_in[12];
    const float* W2    = (const float*)d_in[13];
    const float* b2    = (const float*)d_in[14];
    const float* W3    = (const float*)d_in[15];
    const float* b3    = (const float*)d_in[16];

    float4* wbuf = (float4*)d_ws;                       // 102400 float4 = 1.6375 MB
    float* hseq  = (float*)((char*)d_ws + 102400 * 16); // 256*512*100 fp32 = 52.4 MB

    prep_weights<<<dim3(400), dim3(256), 0, stream>>>(Wih0, Whh0, WihL, WhhL, wbuf);
    gesture_lstm_kernel<<<dim3(256), dim3(NT), 0, stream>>>(
        x, wbuf, b0, bLv, gamma, beta, rmean, rvar, W1, b1, W2, b2, W3, b3,
        (float*)d_out, hseq);
}

// Round 5
// 2435.237 us; speedup vs baseline: 1.0990x; 1.0990x over previous
//
#include <hip/hip_runtime.h>

#define NT 1024
#define TSEQ 512

typedef float float2v __attribute__((ext_vector_type(2)));

__device__ __forceinline__ float sigmoid_(float x) { return 1.0f / (1.0f + __expf(-x)); }
__device__ __forceinline__ float tanh_(float x) { return 1.0f - 2.0f / (1.0f + __expf(2.0f * x)); }

// ---------------- prep kernel: pack weights into task-ordered image ----------------
// Task map (main kernel): f = tid/100 (k-chunk of 20), rg = tid%100 (unit; owns all
// 4 gate rows of unit rg). tid>=1000: zeros.
// wbuf float4 index: (l*20 + g*5 + q)*1024 + tid  ->  W[g*100+rg][20f+4q .. +3]
// Padded K=200 row image: layer0 = [x(5); h(100); 0(95)], layers>=1 = [x(100); h(100)].
extern "C" __global__ void prep_weights(const float* __restrict__ Wih0,
                                        const float* __restrict__ Whh0,
                                        const float* __restrict__ WihL,
                                        const float* __restrict__ WhhL,
                                        float4* __restrict__ wbuf) {
    int gid = blockIdx.x * 256 + threadIdx.x;  // 5*20*1024 = 102400 total
    if (gid >= 102400) return;
    int tid = gid & 1023;
    int lgq = gid >> 10;
    int gq = lgq % 20;          // g*5 + q
    int l = lgq / 20;
    int g = gq / 5, q = gq % 5;
    float tmp[4] = {0.f, 0.f, 0.f, 0.f};
    if (tid < 1000) {
        int f = tid / 100, rg = tid % 100;
        int row = g * 100 + rg;
        int k0 = 20 * f + 4 * q;
        for (int c = 0; c < 4; ++c) {
            int k = k0 + c;
            float w = 0.f;
            if (l == 0) {
                if (k < 5) w = Wih0[row * 5 + k];
                else if (k < 105) w = Whh0[row * 100 + (k - 5)];
            } else {
                if (k < 100) w = WihL[(l - 1) * 40000 + row * 100 + k];
                else w = WhhL[(l - 1) * 40000 + row * 100 + (k - 100)];
            }
            tmp[c] = w;
        }
    }
    wbuf[gid] = make_float4(tmp[0], tmp[1], tmp[2], tmp[3]);
}

// ---------------- main kernel ----------------
// One block per batch element. Thread (f, rg) owns gates {i,f,g,o} of unit rg over
// k in [20f, 20f+20) — 80 weights (40 float2 pairs) in registers, pk_fma inner loop.
template <int IN, bool FIRST, bool STORE>
__device__ void run_layer(const float4* __restrict__ wl, const float* __restrict__ bL,
                          const float* __restrict__ xsrc, float* __restrict__ hdst,
                          int b, int tid, int f, int rg, bool real,
                          float* xh, float4* part4) {
    // weights -> registers: branch-free, constant dest indices
    float2v w[40];  // [g*10 + 2q] = k pair (4q,4q+1), [g*10+2q+1] = (4q+2,4q+3)
#pragma unroll
    for (int g = 0; g < 4; ++g) {
#pragma unroll
        for (int q = 0; q < 5; ++q) {
            float4 t = wl[(g * 5 + q) * 1024 + tid];
            w[g * 10 + 2 * q]     = (float2v){t.x, t.y};
            w[g * 10 + 2 * q + 1] = (float2v){t.z, t.w};
        }
    }
    // combine threads hold their unit's biases in registers
    float bi = 0.f, bf = 0.f, bg = 0.f, bo = 0.f;
    if (tid < 100) {
        bi = bL[tid]; bf = bL[100 + tid]; bg = bL[200 + tid]; bo = bL[300 + tid];
    }

    if (tid < 256) xh[tid] = 0.f;
    __syncthreads();
    if (FIRST) {
        if (tid < 5) xh[tid] = xsrc[b * TSEQ * 5 + tid];
    } else {
        if (tid < 25) ((float4*)xh)[tid] = ((const float4*)xsrc)[b * TSEQ * 25 + tid];
    }
    __syncthreads();

    const float4* xv4 = (const float4*)xh + f * 5;  // chunk base (dummies -> zeros at 200+)
    float c = 0.f, hprev = 0.f;

    for (int t = 0; t < TSEQ; ++t) {
        // delayed h-store: issued at phase top so the barrier drain finds it done
        if (STORE) {
            if (tid < 100 && t > 0) hdst[(b * TSEQ + (t - 1)) * 100 + tid] = hprev;
        }
        // prefetch next-step input (landed after combine)
        int tn = (t + 1 < TSEQ) ? (t + 1) : (TSEQ - 1);
        float pfs = 0.f;
        float4 pf4 = {0.f, 0.f, 0.f, 0.f};
        if (FIRST) {
            if (tid >= 128 && tid < 133) pfs = xsrc[(b * TSEQ + tn) * 5 + (tid - 128)];
        } else {
            if (tid >= 128 && tid < 153) pf4 = ((const float4*)xsrc)[(b * TSEQ + tn) * 25 + (tid - 128)];
        }

        // 80 MACs as 40 v_pk_fma_f32
        float2v a0 = {0.f, 0.f}, a1 = {0.f, 0.f}, a2 = {0.f, 0.f}, a3 = {0.f, 0.f};
#pragma unroll
        for (int q = 0; q < 5; ++q) {
            float4 xq = xv4[q];
            float2v xlo = (float2v){xq.x, xq.y};
            float2v xhi = (float2v){xq.z, xq.w};
            a0 = __builtin_elementwise_fma(w[2 * q],      xlo, a0);
            a0 = __builtin_elementwise_fma(w[2 * q + 1],  xhi, a0);
            a1 = __builtin_elementwise_fma(w[10 + 2 * q],     xlo, a1);
            a1 = __builtin_elementwise_fma(w[10 + 2 * q + 1], xhi, a1);
            a2 = __builtin_elementwise_fma(w[20 + 2 * q],     xlo, a2);
            a2 = __builtin_elementwise_fma(w[20 + 2 * q + 1], xhi, a2);
            a3 = __builtin_elementwise_fma(w[30 + 2 * q],     xlo, a3);
            a3 = __builtin_elementwise_fma(w[30 + 2 * q + 1], xhi, a3);
        }
        if (real) {
            part4[f * 100 + rg] = make_float4(a0.x + a0.y, a1.x + a1.y,
                                              a2.x + a2.y, a3.x + a3.y);
        }
        __syncthreads();

        // combine: thread rg<100 owns unit rg end-to-end
        if (tid < 100) {
            float4 s = part4[tid];
#pragma unroll
            for (int ff = 1; ff < 10; ++ff) {
                float4 tt = part4[ff * 100 + tid];
                s.x += tt.x; s.y += tt.y; s.z += tt.z; s.w += tt.w;
            }
            float gi = sigmoid_(s.x + bi);
            float gf = sigmoid_(s.y + bf);
            float gg = tanh_(s.z + bg);
            float go = sigmoid_(s.w + bo);
            c = gf * c + gi * gg;
            float hv = go * tanh_(c);
            xh[IN + tid] = hv;
            hprev = hv;
        }
        // land prefetched x for t+1
        if (FIRST) {
            if (tid >= 128 && tid < 133) xh[tid - 128] = pfs;
        } else {
            if (tid >= 128 && tid < 153) ((float4*)xh)[tid - 128] = pf4;
        }
        __syncthreads();
    }
    if (STORE) {
        if (tid < 100) hdst[(b * TSEQ + TSEQ - 1) * 100 + tid] = hprev;
    }
}

extern "C" __global__ void __launch_bounds__(NT, 4)
gesture_lstm_kernel(const float* __restrict__ x,
                    const float4* __restrict__ wbuf,
                    const float* __restrict__ b0, const float* __restrict__ bLv,
                    const float* __restrict__ gamma, const float* __restrict__ beta,
                    const float* __restrict__ rmean, const float* __restrict__ rvar,
                    const float* __restrict__ W1, const float* __restrict__ b1,
                    const float* __restrict__ W2, const float* __restrict__ b2,
                    const float* __restrict__ W3, const float* __restrict__ b3,
                    float* __restrict__ out, float* __restrict__ hseq) {
    __shared__ __align__(16) float xh[256];
    __shared__ __align__(16) float4 part4[1000];
    __shared__ __align__(16) float hw[10000];

    int tid = threadIdx.x;
    int b = blockIdx.x;
    int f = tid / 100;   // 10 for dummies -> xv4 reads land in xh[200..220) (zeroed)
    int rg = tid % 100;
    bool real = tid < 1000;

    run_layer<5,   true,  true >(wbuf + 0 * 20480, b0,         x,    hseq, b, tid, f, rg, real, xh, part4);
    run_layer<100, false, true >(wbuf + 1 * 20480, bLv + 0,    hseq, hseq, b, tid, f, rg, real, xh, part4);
    run_layer<100, false, true >(wbuf + 2 * 20480, bLv + 400,  hseq, hseq, b, tid, f, rg, real, xh, part4);
    run_layer<100, false, true >(wbuf + 3 * 20480, bLv + 800,  hseq, hseq, b, tid, f, rg, real, xh, part4);
    run_layer<100, false, false>(wbuf + 4 * 20480, bLv + 1200, hseq, hseq, b, tid, f, rg, real, xh, part4);

    // ---- head: BN (inference) -> FC1+ReLU -> FC2+ReLU -> FC3 ----
    float* fcbuf = (float*)part4;
    if (tid < 100) {
        float hv = xh[100 + tid];
        xh[tid] = (hv - rmean[tid]) * rsqrtf(rvar[tid] + 1e-5f) * gamma[tid] + beta[tid];
    }
    __syncthreads();

    for (int i = tid; i < 2500; i += NT) ((float4*)hw)[i] = ((const float4*)W1)[i];
    __syncthreads();
    if (tid < 100) {
        float acc = b1[tid];
#pragma unroll
        for (int k = 0; k < 100; ++k) acc = fmaf(hw[tid * 100 + k], xh[k], acc);
        fcbuf[tid] = fmaxf(acc, 0.0f);
    }
    __syncthreads();

    for (int i = tid; i < 2500; i += NT) ((float4*)hw)[i] = ((const float4*)W2)[i];
    __syncthreads();
    if (tid < 100) {
        float acc = b2[tid];
#pragma unroll
        for (int k = 0; k < 100; ++k) acc = fmaf(hw[tid * 100 + k], fcbuf[k], acc);
        fcbuf[400 + tid] = fmaxf(acc, 0.0f);
    }
    __syncthreads();

    if (tid < 3) {
        float acc = b3[tid];
#pragma unroll
        for (int k = 0; k < 100; ++k) acc = fmaf(W3[tid * 100 + k], fcbuf[400 + k], acc);
        out[b * 3 + tid] = acc;
    }
}

extern "C" void kernel_launch(void* const* d_in, const int* in_sizes, int n_in,
                              void* d_out, int out_size, void* d_ws, size_t ws_size,
                              hipStream_t stream) {
    const float* x     = (const float*)d_in[0];
    const float* Wih0  = (const float*)d_in[1];
    const float* Whh0  = (const float*)d_in[2];
    const float* b0    = (const float*)d_in[3];
    const float* WihL  = (const float*)d_in[4];
    const float* WhhL  = (const float*)d_in[5];
    const float* bLv   = (const float*)d_in[6];
    const float* gamma = (const float*)d_in[7];
    const float* beta  = (const float*)d_in[8];
    const float* rmean = (const float*)d_in[9];
    const float* rvar  = (const float*)d_in[10];
    const float* W1    = (const float*)d_in[11];
    const float* b1    = (const float*)d_in[12];
    const float* W2    = (const float*)d_in[13];
    const float* b2    = (const float*)d_in[14];
    const float* W3    = (const float*)d_in[15];
    const float* b3    = (const float*)d_in[16];

    float4* wbuf = (float4*)d_ws;                       // 102400 float4 = 1.6375 MB
    float* hseq  = (float*)((char*)d_ws + 102400 * 16); // 256*512*100 fp32 = 52.4 MB

    prep_weights<<<dim3(400), dim3(256), 0, stream>>>(Wih0, Whh0, WihL, WhhL, wbuf);
    gesture_lstm_kernel<<<dim3(256), dim3(NT), 0, stream>>>(
        x, wbuf, b0, bLv, gamma, beta, rmean, rvar, W1, b1, W2, b2, W3, b3,
        (float*)d_out, hseq);
}